// Round 11
// baseline (435.581 us; speedup 1.0000x reference)
//
#include <hip/hip_runtime.h>
#include <hip/hip_bf16.h>
#include <math.h>

#define N_NODES  20000
#define E_EDGES  320000
#define E_TOT    (E_EDGES + N_NODES)
#define F_INF    256
#define HEADS    8
#define CDIM     64
#define HID      512
#define B_GRAPHS 64
#define NCLS     10
#define M_PAD    20096          // 157 * 128
#define NSCAN    20             // ceil(20000/1024)
#define NWG_GEMM 1256           // 157 row-panels * 8 col-tiles (64 wide)

typedef __attribute__((ext_vector_type(8))) short short8;
typedef __attribute__((ext_vector_type(4))) float f32x4;

__device__ inline unsigned short f2bf(float x) {
    unsigned u = __builtin_bit_cast(unsigned, x);
    u += 0x7fff + ((u >> 16) & 1);          // round-to-nearest-even
    return (unsigned short)(u >> 16);
}
__device__ inline float bf2f(unsigned short h) {
    unsigned u = ((unsigned)h) << 16;
    return __builtin_bit_cast(float, u);
}

#define GLOAD_LDS16(g, l) __builtin_amdgcn_global_load_lds(                     \
        (const __attribute__((address_space(1))) void*)(g),                     \
        (__attribute__((address_space(3))) void*)(l), 16, 0, 0)

// ---------------------------------------------------------------- fp32 -> bf16 hi/lo split (row-padded)
__global__ __launch_bounds__(256) void split_pad(const float* __restrict__ src,
                                                 unsigned short* __restrict__ hi,
                                                 unsigned short* __restrict__ lo,
                                                 int M, int K, long total) {
    long i = ((long)blockIdx.x * 256 + threadIdx.x) * 4;
    if (i >= total) return;
    int row = (int)(i / K);
    float4 v = make_float4(0.f, 0.f, 0.f, 0.f);
    if (row < M) v = *(const float4*)(src + i);
    ushort4 h, l;
    h.x = f2bf(v.x); l.x = f2bf(v.x - bf2f(h.x));
    h.y = f2bf(v.y); l.y = f2bf(v.y - bf2f(h.y));
    h.z = f2bf(v.z); l.z = f2bf(v.z - bf2f(h.z));
    h.w = f2bf(v.w); l.w = f2bf(v.w - bf2f(h.w));
    *(ushort4*)(hi + i) = h;
    *(ushort4*)(lo + i) = l;
}

// ---------------------------------------------------------------- B[K][512] -> Bt_hi/lo[512][K]
__global__ __launch_bounds__(256) void transpose_split_B(const float* __restrict__ B,
                                                         unsigned short* __restrict__ Bthi,
                                                         unsigned short* __restrict__ Btlo,
                                                         int K) {
    __shared__ float t[32][33];
    int n0 = blockIdx.x * 32, k0 = blockIdx.y * 32;
    int tx = threadIdx.x & 31, ty = threadIdx.x >> 5;     // 32 x 8
    for (int i = ty; i < 32; i += 8) t[i][tx] = B[(size_t)(k0 + i) * HID + n0 + tx];
    __syncthreads();
    for (int i = ty; i < 32; i += 8) {
        float v = t[tx][i];                                // = B[k0+tx][n0+i]
        unsigned short h = f2bf(v);
        unsigned short l = f2bf(v - bf2f(h));
        Bthi[(size_t)(n0 + i) * K + k0 + tx] = h;
        Btlo[(size_t)(n0 + i) * K + k0 + tx] = l;
    }
}

// ---------------------------------------------------------------- bf16x3 MFMA GEMM, 128x64 tile (occupancy-sized):
// grid = 1256 = 4.9 blocks/CU; 24KB LDS single buffer -> 4-5 resident blocks/CU hide the barrier drain.
__global__ __launch_bounds__(256) void gemm_mfma(const unsigned short* __restrict__ Ahi,
                                                 const unsigned short* __restrict__ Alo,
                                                 const unsigned short* __restrict__ Bhi,
                                                 const unsigned short* __restrict__ Blo,
                                                 const float* __restrict__ a_src,
                                                 const float* __restrict__ a_dst,
                                                 unsigned short* __restrict__ xtb,
                                                 float* __restrict__ al_s,
                                                 float* __restrict__ al_d,
                                                 int M, int K) {
    __shared__ short AsHi[4096], AsLo[4096], BsHi[2048], BsLo[2048];   // 24 KB
    const int tid = threadIdx.x;
    const int w = tid >> 6, lane = tid & 63;

    // bijective XCD-chunked swizzle: nwg=1256, q=157, r=0 -> wg = xcd*157 + idx
    const int xcd = blockIdx.x & 7, idx = blockIdx.x >> 3;
    const int wg = xcd * (NWG_GEMM >> 3) + idx;
    const int row0 = (wg >> 3) * 128, col0 = (wg & 7) * 64;

    long offA[2];
    int ldsA[2];
#pragma unroll
    for (int i = 0; i < 2; ++i) {
        int u = w * 128 + i * 64 + lane;
        int row = u >> 2;
        int kg = (u & 3) ^ ((row >> 1) & 3);               // inverse of read swizzle
        offA[i] = ((long)(row0 + row) * K + kg * 8) * 2;   // bytes
        ldsA[i] = (w * 128 + i * 64) * 8;                  // short index
    }
    long offB;
    int ldsB;
    {
        int u = w * 64 + lane;
        int row = u >> 2;
        int kg = (u & 3) ^ ((row >> 1) & 3);
        offB = ((long)(col0 + row) * K + kg * 8) * 2;
        ldsB = (w * 64) * 8;
    }

    const int r16 = lane & 15, kg = lane >> 4;
    int aOff[2], bOff[4];
#pragma unroll
    for (int i = 0; i < 2; ++i) {
        int row = w * 32 + i * 16 + r16;
        aOff[i] = (row * 4 + (kg ^ ((row >> 1) & 3))) * 16;
    }
#pragma unroll
    for (int j = 0; j < 4; ++j) {
        int col = j * 16 + r16;
        bOff[j] = (col * 4 + (kg ^ ((col >> 1) & 3))) * 16;
    }

    const char* pAhi = (const char*)Ahi;
    const char* pAlo = (const char*)Alo;
    const char* pBhi = (const char*)Bhi;
    const char* pBlo = (const char*)Blo;

    f32x4 acc[2][4] = {};

    for (int kk = 0; kk < K; kk += 32) {
        long kb = (long)kk * 2;
        __syncthreads();                 // previous step's ds_reads done
#pragma unroll
        for (int i = 0; i < 2; ++i) {
            GLOAD_LDS16(pAhi + offA[i] + kb, AsHi + ldsA[i]);
            GLOAD_LDS16(pAlo + offA[i] + kb, AsLo + ldsA[i]);
        }
        GLOAD_LDS16(pBhi + offB + kb, BsHi + ldsB);
        GLOAD_LDS16(pBlo + offB + kb, BsLo + ldsB);
        __syncthreads();                 // drains vmcnt; other resident blocks run through this

        short8 fah[2], fal[2], fbh[4], fbl[4];
#pragma unroll
        for (int i = 0; i < 2; ++i) {
            fah[i] = *(const short8*)((const char*)AsHi + aOff[i]);
            fal[i] = *(const short8*)((const char*)AsLo + aOff[i]);
        }
#pragma unroll
        for (int j = 0; j < 4; ++j) {
            fbh[j] = *(const short8*)((const char*)BsHi + bOff[j]);
            fbl[j] = *(const short8*)((const char*)BsLo + bOff[j]);
        }
#pragma unroll
        for (int i = 0; i < 2; ++i)
#pragma unroll
            for (int j = 0; j < 4; ++j) {
                acc[i][j] = __builtin_amdgcn_mfma_f32_16x16x32_bf16(fah[i], fbh[j], acc[i][j], 0, 0, 0);
                acc[i][j] = __builtin_amdgcn_mfma_f32_16x16x32_bf16(fah[i], fbl[j], acc[i][j], 0, 0, 0);
                acc[i][j] = __builtin_amdgcn_mfma_f32_16x16x32_bf16(fal[i], fbh[j], acc[i][j], 0, 0, 0);
            }
    }

    // ---- epilogue. C/D layout: col=lane&15 within 16-block, row=(lane>>4)*4+rr.
    const int h = col0 >> 6;
    float asv[4], adv[4];
#pragma unroll
    for (int j = 0; j < 4; ++j) {
        asv[j] = a_src[h * CDIM + j * 16 + r16];
        adv[j] = a_dst[h * CDIM + j * 16 + r16];
    }
#pragma unroll
    for (int i = 0; i < 2; ++i) {
        int rbase = row0 + w * 32 + i * 16 + (lane >> 4) * 4;
#pragma unroll
        for (int rr = 0; rr < 4; ++rr) {
            float ss = acc[i][0][rr] * asv[0] + acc[i][1][rr] * asv[1]
                     + acc[i][2][rr] * asv[2] + acc[i][3][rr] * asv[3];
            float dd = acc[i][0][rr] * adv[0] + acc[i][1][rr] * adv[1]
                     + acc[i][2][rr] * adv[2] + acc[i][3][rr] * adv[3];
#pragma unroll
            for (int off = 1; off < 16; off <<= 1) {
                ss += __shfl_xor(ss, off);
                dd += __shfl_xor(dd, off);
            }
            int row = rbase + rr;
            if ((lane & 15) == 0 && row < M) {
                al_s[row * HEADS + h] = ss;
                al_d[row * HEADS + h] = dd;
            }
        }
#pragma unroll
        for (int j = 0; j < 4; ++j) {
            int col = col0 + j * 16 + r16;
#pragma unroll
            for (int rr = 0; rr < 4; ++rr)
                if (rbase + rr < M) xtb[(size_t)(rbase + rr) * HID + col] = f2bf(acc[i][j][rr]);
        }
    }
}

// ---------------------------------------------------------------- CSR build
__global__ __launch_bounds__(256) void count_edges(const int* __restrict__ ei,
                                                   int* __restrict__ counts) {
    int e = blockIdx.x * 256 + threadIdx.x;
    if (e < E_TOT) {
        int dst = (e < E_EDGES) ? ei[E_EDGES + e] : (e - E_EDGES);
        atomicAdd(&counts[dst], 1);
    }
}

// scan_local + find_bounds folded (block 0 also binary-searches graph bounds)
__global__ __launch_bounds__(1024) void scan_local(const int* __restrict__ counts,
                                                   int* __restrict__ incl,
                                                   int* __restrict__ bsum,
                                                   const int* __restrict__ batch,
                                                   int* __restrict__ bounds) {
    __shared__ int s[1024];
    int tid = threadIdx.x;
    int i = blockIdx.x * 1024 + tid;
    if (blockIdx.x == 0 && tid <= B_GRAPHS) {
        int lo = 0, hi = N_NODES;
        while (lo < hi) {
            int mid = (lo + hi) >> 1;
            if (batch[mid] < tid) lo = mid + 1; else hi = mid;
        }
        bounds[tid] = lo;
    }
    int v = (i < N_NODES) ? counts[i] : 0;
    s[tid] = v;
    __syncthreads();
    for (int off = 1; off < 1024; off <<= 1) {
        int t = (tid >= off) ? s[tid - off] : 0;
        __syncthreads();
        s[tid] += t;
        __syncthreads();
    }
    if (i < N_NODES) incl[i] = s[tid];
    if (tid == 1023) bsum[blockIdx.x] = s[1023];
}

// scan_finalize with inline block-prefix (<=20 ints, summed by thread 0)
__global__ __launch_bounds__(1024) void scan_finalize(const int* __restrict__ counts,
                                                      const int* __restrict__ incl,
                                                      const int* __restrict__ bsum,
                                                      int* __restrict__ offsets,
                                                      int* __restrict__ cursor) {
    __shared__ int bpre_s;
    if (threadIdx.x == 0) {
        int s = 0;
        for (int j = 0; j < blockIdx.x; ++j) s += bsum[j];
        bpre_s = s;
    }
    __syncthreads();
    int i = blockIdx.x * 1024 + threadIdx.x;
    if (i < N_NODES) {
        int inc = incl[i] + bpre_s;
        offsets[i + 1] = inc;
        cursor[i] = inc - counts[i];
    }
    if (i == 0) offsets[0] = 0;
}

// stores srcn DIRECTLY (self-loop: srcn = dst) -> aggregation needs no ei load, no branch
__global__ __launch_bounds__(256) void scatter_edges(const int* __restrict__ ei,
                                                     int* __restrict__ cursor,
                                                     int* __restrict__ csr) {
    int e = blockIdx.x * 256 + threadIdx.x;
    if (e < E_TOT) {
        int srcn, dst;
        if (e < E_EDGES) { srcn = ei[e]; dst = ei[E_EDGES + e]; }
        else             { srcn = dst = e - E_EDGES; }
        int pos = atomicAdd(&cursor[dst], 1);
        csr[pos] = srcn;
    }
}

// ---------------------------------------------------------------- GAT aggregation: wave handles TWO nodes (interleaved
// independent load chains -> 2x memory-level parallelism). Lane owns 8 channels of each node; guards wave-uniform.
__global__ __launch_bounds__(256) void gat_aggregate5(const unsigned short* __restrict__ xtb,
                                                      const float* __restrict__ al_s,
                                                      const float* __restrict__ al_d,
                                                      const int* __restrict__ offsets,
                                                      const int* __restrict__ csr,
                                                      const float* __restrict__ bias,
                                                      unsigned short* __restrict__ outHi,
                                                      unsigned short* __restrict__ outLo) {
    const int lane = threadIdx.x & 63;
    const int n0 = blockIdx.x * 8 + (threadIdx.x >> 6) * 2;
    const int n1 = n0 + 1;
    const int h = lane >> 3;            // head of this lane's channels
    const int c0 = lane * 8;            // channels c0..c0+7
    const int beg0 = offsets[n0], deg0 = offsets[n0 + 1] - beg0;
    const int beg1 = offsets[n1], deg1 = offsets[n1 + 1] - beg1;
    const float ald0 = al_d[n0 * HEADS + h];
    const float ald1 = al_d[n1 * HEADS + h];

    float acc0[8] = {}, acc1[8] = {};
    float ps0 = 0.f, ps1 = 0.f;
    const int dm = max(deg0, deg1);

    for (int i = 0; i < dm; ++i) {
        if (i < deg0) {                                     // wave-uniform guard
            int s = csr[beg0 + i];
            float ev = al_s[s * HEADS + h] + ald0;
            ev = (ev >= 0.f) ? ev : 0.2f * ev;
            float p = __expf(ev);
            ps0 += p;
            short8 row = *(const short8*)(xtb + (size_t)s * HID + c0);
#pragma unroll
            for (int j = 0; j < 8; ++j)
                acc0[j] = fmaf(p, bf2f((unsigned short)row[j]), acc0[j]);
        }
        if (i < deg1) {                                     // wave-uniform guard
            int s = csr[beg1 + i];
            float ev = al_s[s * HEADS + h] + ald1;
            ev = (ev >= 0.f) ? ev : 0.2f * ev;
            float p = __expf(ev);
            ps1 += p;
            short8 row = *(const short8*)(xtb + (size_t)s * HID + c0);
#pragma unroll
            for (int j = 0; j < 8; ++j)
                acc1[j] = fmaf(p, bf2f((unsigned short)row[j]), acc1[j]);
        }
    }

    float4 b0 = *(const float4*)(bias + c0);
    float4 b1 = *(const float4*)(bias + c0 + 4);
    float bv[8] = { b0.x, b0.y, b0.z, b0.w, b1.x, b1.y, b1.z, b1.w };

    const float inv0 = 1.f / (ps0 + 1e-16f);
    const float inv1 = 1.f / (ps1 + 1e-16f);
    short8 h8, l8;
#pragma unroll
    for (int j = 0; j < 8; ++j) {
        float v = acc0[j] * inv0 + bv[j];
        v = (v > 0.f) ? v : expm1f(v);      // ELU
        unsigned short hi = f2bf(v);
        h8[j] = (short)hi;
        l8[j] = (short)f2bf(v - bf2f(hi));
    }
    size_t o0 = (size_t)n0 * HID + c0;
    *(short8*)(outHi + o0) = h8;
    *(short8*)(outLo + o0) = l8;
#pragma unroll
    for (int j = 0; j < 8; ++j) {
        float v = acc1[j] * inv1 + bv[j];
        v = (v > 0.f) ? v : expm1f(v);      // ELU
        unsigned short hi = f2bf(v);
        h8[j] = (short)hi;
        l8[j] = (short)f2bf(v - bf2f(hi));
    }
    size_t o1 = (size_t)n1 * HID + c0;
    *(short8*)(outHi + o1) = h8;
    *(short8*)(outLo + o1) = l8;
}

// ---------------------------------------------------------------- pooling stage A:
// grid (B_GRAPHS, 8 ch-blocks, 4 node-splits); 8 nodes in flight per block
__global__ __launch_bounds__(256) void pool_partial(const unsigned short* __restrict__ hHi,
                                                    const unsigned short* __restrict__ hLo,
                                                    const int* __restrict__ bounds,
                                                    float* __restrict__ partial) {
    const int b = blockIdx.x, y = blockIdx.y, k = blockIdx.z;
    const int s = bounds[b], cnt = bounds[b + 1] - s;
    const int ns = s + (cnt * k) / 4;
    const int ne = s + (cnt * (k + 1)) / 4;
    const int t = threadIdx.x;
    const int chp = t & 31;            // u32 pair within 64-ch block
    const int nl = t >> 5;             // 0..7

    float a0 = 0.f, a1 = 0.f;
    for (int n = ns + nl; n < ne; n += 8) {
        size_t off = (size_t)n * HID + y * 64 + chp * 2;
        unsigned vh = *(const unsigned*)(hHi + off);
        unsigned vl = *(const unsigned*)(hLo + off);
        a0 += bf2f((unsigned short)(vh & 0xffff)) + bf2f((unsigned short)(vl & 0xffff));
        a1 += bf2f((unsigned short)(vh >> 16)) + bf2f((unsigned short)(vl >> 16));
    }
    __shared__ float red[4][32][2];
    a0 += __shfl_xor(a0, 32);
    a1 += __shfl_xor(a1, 32);
    if ((t & 63) < 32) { red[t >> 6][chp][0] = a0; red[t >> 6][chp][1] = a1; }
    __syncthreads();
    if (t < 64) {
        int cp = t >> 1, c = t & 1;
        float v = red[0][cp][c] + red[1][cp][c] + red[2][cp][c] + red[3][cp][c];
        partial[(((size_t)k * B_GRAPHS + b) * 8 + y) * 64 + cp * 2 + c] = v;
    }
}

// ---------------------------------------------------------------- pool stage B + classifier + softmax (merged)
__global__ __launch_bounds__(512) void pool_classify(const float* __restrict__ partial,
                                                     const int* __restrict__ bounds,
                                                     const float* __restrict__ Wl,
                                                     const float* __restrict__ bl,
                                                     float* __restrict__ hG,
                                                     float* __restrict__ outP) {
    const int b = blockIdx.x, t = threadIdx.x;
    __shared__ float row[HID];
    __shared__ float logit[NCLS];
    float v = 0.f;
#pragma unroll
    for (int k = 0; k < 4; ++k)
        v += partial[((size_t)k * B_GRAPHS + b) * HID + t];
    float cnt = fmaxf((float)(bounds[b + 1] - bounds[b]), 1.0f);
    v /= cnt;
    hG[b * HID + t] = v;
    row[t] = v;
    __syncthreads();
    if (t < NCLS) {
        float acc = bl[t];
        for (int j = 0; j < HID; ++j) acc += row[j] * Wl[j * NCLS + t];
        logit[t] = acc;
    }
    __syncthreads();
    if (t == 0) {
        float mx = logit[0];
        for (int k = 1; k < NCLS; ++k) mx = fmaxf(mx, logit[k]);
        float ssum = 0.f, ex[NCLS];
        for (int k = 0; k < NCLS; ++k) { ex[k] = expf(logit[k] - mx); ssum += ex[k]; }
        for (int k = 0; k < NCLS; ++k) outP[b * NCLS + k] = ex[k] / ssum;
    }
}

// ---------------------------------------------------------------- launch
extern "C" void kernel_launch(void* const* d_in, const int* in_sizes, int n_in,
                              void* d_out, int out_size, void* d_ws, size_t ws_size,
                              hipStream_t stream) {
    const float* x     = (const float*)d_in[0];
    const int*   ei    = (const int*)d_in[1];
    const int*   batch = (const int*)d_in[2];
    const float* W[3]  = { (const float*)d_in[3], (const float*)d_in[7],  (const float*)d_in[11] };
    const float* as_[3] = { (const float*)d_in[4], (const float*)d_in[8],  (const float*)d_in[12] };
    const float* ad_[3] = { (const float*)d_in[5], (const float*)d_in[9],  (const float*)d_in[13] };
    const float* bb[3] = { (const float*)d_in[6], (const float*)d_in[10], (const float*)d_in[14] };
    const float* Wl    = (const float*)d_in[15];
    const float* bl    = (const float*)d_in[16];

    // workspace layout
    char* ws = (char*)d_ws;
    unsigned short* A1hi = (unsigned short*)ws;      ws += (size_t)M_PAD * F_INF * 2;  // 10.3 MB
    unsigned short* A1lo = (unsigned short*)ws;      ws += (size_t)M_PAD * F_INF * 2;
    unsigned short* A2hi = (unsigned short*)ws;      ws += (size_t)M_PAD * HID * 2;    // 20.6 MB
    unsigned short* A2lo = (unsigned short*)ws;      ws += (size_t)M_PAD * HID * 2;
    unsigned short* Bthi = (unsigned short*)ws;      ws += (size_t)HID * HID * 2;      // 0.5 MB
    unsigned short* Btlo = (unsigned short*)ws;      ws += (size_t)HID * HID * 2;
    unsigned short* xtb  = (unsigned short*)ws;      ws += (size_t)N_NODES * HID * 2;  // 20.5 MB
    float* als  = (float*)ws;                        ws += (size_t)N_NODES * HEADS * 4;
    float* ald  = (float*)ws;                        ws += (size_t)N_NODES * HEADS * 4;
    float* partial = (float*)ws;                     ws += (size_t)4 * B_GRAPHS * HID * 4; // 512 KB
    int* counts  = (int*)ws;                         ws += (size_t)N_NODES * 4;
    int* incl    = (int*)ws;                         ws += (size_t)N_NODES * 4;
    int* bsum    = (int*)ws;                         ws += 32 * 4;
    int* offsets = (int*)ws;                         ws += (size_t)(N_NODES + 1) * 4;
    int* cursor  = (int*)ws;                         ws += (size_t)N_NODES * 4;
    int* csr     = (int*)ws;                         ws += (size_t)E_TOT * 4;
    int* bounds  = (int*)ws;                         ws += (size_t)(B_GRAPHS + 1) * 4;

    float* hG = (float*)d_out;                 // 64*512
    float* probs = (float*)d_out + (size_t)B_GRAPHS * HID;

    // ---- CSR build (identical every call; rebuilt for determinism/no-caching)
    hipMemsetAsync(counts, 0, (size_t)N_NODES * 4, stream);
    count_edges<<<(E_TOT + 255) / 256, 256, 0, stream>>>(ei, counts);
    scan_local<<<NSCAN, 1024, 0, stream>>>(counts, incl, bsum, batch, bounds);
    scan_finalize<<<NSCAN, 1024, 0, stream>>>(counts, incl, bsum, offsets, cursor);
    scatter_edges<<<(E_TOT + 255) / 256, 256, 0, stream>>>(ei, cursor, csr);
    hipMemsetAsync(A2hi + (size_t)N_NODES * HID, 0, (size_t)(M_PAD - N_NODES) * HID * 2, stream);
    hipMemsetAsync(A2lo + (size_t)N_NODES * HID, 0, (size_t)(M_PAD - N_NODES) * HID * 2, stream);

    // ---- layer 1 (K = 256)
    {
        long totA = (long)M_PAD * F_INF;
        split_pad<<<(int)(totA / 4 / 256), 256, 0, stream>>>(x, A1hi, A1lo, N_NODES, F_INF, totA);
        transpose_split_B<<<dim3(HID / 32, F_INF / 32), 256, 0, stream>>>(W[0], Bthi, Btlo, F_INF);
        gemm_mfma<<<NWG_GEMM, 256, 0, stream>>>(A1hi, A1lo, Bthi, Btlo, as_[0], ad_[0],
                                                xtb, als, ald, N_NODES, F_INF);
        gat_aggregate5<<<N_NODES / 8, 256, 0, stream>>>(xtb, als, ald, offsets, csr, bb[0], A2hi, A2lo);
    }

    // ---- layers 2,3 (K = 512)
    for (int L = 1; L < 3; ++L) {
        transpose_split_B<<<dim3(HID / 32, HID / 32), 256, 0, stream>>>(W[L], Bthi, Btlo, HID);
        gemm_mfma<<<NWG_GEMM, 256, 0, stream>>>(A2hi, A2lo, Bthi, Btlo, as_[L], ad_[L],
                                                xtb, als, ald, N_NODES, HID);
        gat_aggregate5<<<N_NODES / 8, 256, 0, stream>>>(xtb, als, ald, offsets, csr, bb[L], A2hi, A2lo);
    }

    // ---- pool + classify
    {
        dim3 pgrid(B_GRAPHS, 8, 4);
        pool_partial<<<pgrid, 256, 0, stream>>>(A2hi, A2lo, bounds, partial);
        pool_classify<<<B_GRAPHS, 512, 0, stream>>>(partial, bounds, Wl, bl, hG, probs);
    }
}

// Round 12
// 379.365 us; speedup vs baseline: 1.1482x; 1.1482x over previous
//
#include <hip/hip_runtime.h>
#include <hip/hip_bf16.h>
#include <math.h>

#define N_NODES  20000
#define E_EDGES  320000
#define E_TOT    (E_EDGES + N_NODES)
#define F_INF    256
#define HEADS    8
#define CDIM     64
#define HID      512
#define B_GRAPHS 64
#define NCLS     10
#define M_PAD    20096          // 157 * 128
#define NSCAN    20             // ceil(20000/1024)
#define NWG_GEMM 1256           // 157 row-panels * 8 col-tiles (64 wide)

typedef __attribute__((ext_vector_type(8))) short short8;
typedef __attribute__((ext_vector_type(4))) float f32x4;

__device__ inline unsigned short f2bf(float x) {
    unsigned u = __builtin_bit_cast(unsigned, x);
    u += 0x7fff + ((u >> 16) & 1);          // round-to-nearest-even
    return (unsigned short)(u >> 16);
}
__device__ inline float bf2f(unsigned short h) {
    unsigned u = ((unsigned)h) << 16;
    return __builtin_bit_cast(float, u);
}

#define GLOAD_LDS16(g, l) __builtin_amdgcn_global_load_lds(                     \
        (const __attribute__((address_space(1))) void*)(g),                     \
        (__attribute__((address_space(3))) void*)(l), 16, 0, 0)

// ---------------------------------------------------------------- fp32 -> bf16 hi/lo split (row-padded)
__global__ __launch_bounds__(256) void split_pad(const float* __restrict__ src,
                                                 unsigned short* __restrict__ hi,
                                                 unsigned short* __restrict__ lo,
                                                 int M, int K, long total) {
    long i = ((long)blockIdx.x * 256 + threadIdx.x) * 4;
    if (i >= total) return;
    int row = (int)(i / K);
    float4 v = make_float4(0.f, 0.f, 0.f, 0.f);
    if (row < M) v = *(const float4*)(src + i);
    ushort4 h, l;
    h.x = f2bf(v.x); l.x = f2bf(v.x - bf2f(h.x));
    h.y = f2bf(v.y); l.y = f2bf(v.y - bf2f(h.y));
    h.z = f2bf(v.z); l.z = f2bf(v.z - bf2f(h.z));
    h.w = f2bf(v.w); l.w = f2bf(v.w - bf2f(h.w));
    *(ushort4*)(hi + i) = h;
    *(ushort4*)(lo + i) = l;
}

// ---------------------------------------------------------------- B[K][512] -> Bt_hi/lo[512][K]
__global__ __launch_bounds__(256) void transpose_split_B(const float* __restrict__ B,
                                                         unsigned short* __restrict__ Bthi,
                                                         unsigned short* __restrict__ Btlo,
                                                         int K) {
    __shared__ float t[32][33];
    int n0 = blockIdx.x * 32, k0 = blockIdx.y * 32;
    int tx = threadIdx.x & 31, ty = threadIdx.x >> 5;     // 32 x 8
    for (int i = ty; i < 32; i += 8) t[i][tx] = B[(size_t)(k0 + i) * HID + n0 + tx];
    __syncthreads();
    for (int i = ty; i < 32; i += 8) {
        float v = t[tx][i];                                // = B[k0+tx][n0+i]
        unsigned short h = f2bf(v);
        unsigned short l = f2bf(v - bf2f(h));
        Bthi[(size_t)(n0 + i) * K + k0 + tx] = h;
        Btlo[(size_t)(n0 + i) * K + k0 + tx] = l;
    }
}

// ---------------------------------------------------------------- bf16x3 MFMA GEMM, 128x64 tile (occupancy-sized):
// grid = 1256 = 4.9 blocks/CU; 24KB LDS single buffer -> 4-5 resident blocks/CU hide the barrier drain.
__global__ __launch_bounds__(256) void gemm_mfma(const unsigned short* __restrict__ Ahi,
                                                 const unsigned short* __restrict__ Alo,
                                                 const unsigned short* __restrict__ Bhi,
                                                 const unsigned short* __restrict__ Blo,
                                                 const float* __restrict__ a_src,
                                                 const float* __restrict__ a_dst,
                                                 unsigned short* __restrict__ xtb,
                                                 float* __restrict__ al_s,
                                                 float* __restrict__ al_d,
                                                 int M, int K) {
    __shared__ short AsHi[4096], AsLo[4096], BsHi[2048], BsLo[2048];   // 24 KB
    const int tid = threadIdx.x;
    const int w = tid >> 6, lane = tid & 63;

    // bijective XCD-chunked swizzle: nwg=1256, q=157, r=0 -> wg = xcd*157 + idx
    const int xcd = blockIdx.x & 7, idx = blockIdx.x >> 3;
    const int wg = xcd * (NWG_GEMM >> 3) + idx;
    const int row0 = (wg >> 3) * 128, col0 = (wg & 7) * 64;

    long offA[2];
    int ldsA[2];
#pragma unroll
    for (int i = 0; i < 2; ++i) {
        int u = w * 128 + i * 64 + lane;
        int row = u >> 2;
        int kg = (u & 3) ^ ((row >> 1) & 3);               // inverse of read swizzle
        offA[i] = ((long)(row0 + row) * K + kg * 8) * 2;   // bytes
        ldsA[i] = (w * 128 + i * 64) * 8;                  // short index
    }
    long offB;
    int ldsB;
    {
        int u = w * 64 + lane;
        int row = u >> 2;
        int kg = (u & 3) ^ ((row >> 1) & 3);
        offB = ((long)(col0 + row) * K + kg * 8) * 2;
        ldsB = (w * 64) * 8;
    }

    const int r16 = lane & 15, kg = lane >> 4;
    int aOff[2], bOff[4];
#pragma unroll
    for (int i = 0; i < 2; ++i) {
        int row = w * 32 + i * 16 + r16;
        aOff[i] = (row * 4 + (kg ^ ((row >> 1) & 3))) * 16;
    }
#pragma unroll
    for (int j = 0; j < 4; ++j) {
        int col = j * 16 + r16;
        bOff[j] = (col * 4 + (kg ^ ((col >> 1) & 3))) * 16;
    }

    const char* pAhi = (const char*)Ahi;
    const char* pAlo = (const char*)Alo;
    const char* pBhi = (const char*)Bhi;
    const char* pBlo = (const char*)Blo;

    f32x4 acc[2][4] = {};

    for (int kk = 0; kk < K; kk += 32) {
        long kb = (long)kk * 2;
        __syncthreads();                 // previous step's ds_reads done
#pragma unroll
        for (int i = 0; i < 2; ++i) {
            GLOAD_LDS16(pAhi + offA[i] + kb, AsHi + ldsA[i]);
            GLOAD_LDS16(pAlo + offA[i] + kb, AsLo + ldsA[i]);
        }
        GLOAD_LDS16(pBhi + offB + kb, BsHi + ldsB);
        GLOAD_LDS16(pBlo + offB + kb, BsLo + ldsB);
        __syncthreads();                 // drains vmcnt; other resident blocks run through this

        short8 fah[2], fal[2], fbh[4], fbl[4];
#pragma unroll
        for (int i = 0; i < 2; ++i) {
            fah[i] = *(const short8*)((const char*)AsHi + aOff[i]);
            fal[i] = *(const short8*)((const char*)AsLo + aOff[i]);
        }
#pragma unroll
        for (int j = 0; j < 4; ++j) {
            fbh[j] = *(const short8*)((const char*)BsHi + bOff[j]);
            fbl[j] = *(const short8*)((const char*)BsLo + bOff[j]);
        }
#pragma unroll
        for (int i = 0; i < 2; ++i)
#pragma unroll
            for (int j = 0; j < 4; ++j) {
                acc[i][j] = __builtin_amdgcn_mfma_f32_16x16x32_bf16(fah[i], fbh[j], acc[i][j], 0, 0, 0);
                acc[i][j] = __builtin_amdgcn_mfma_f32_16x16x32_bf16(fah[i], fbl[j], acc[i][j], 0, 0, 0);
                acc[i][j] = __builtin_amdgcn_mfma_f32_16x16x32_bf16(fal[i], fbh[j], acc[i][j], 0, 0, 0);
            }
    }

    // ---- epilogue. C/D layout: col=lane&15 within 16-block, row=(lane>>4)*4+rr.
    const int h = col0 >> 6;
    float asv[4], adv[4];
#pragma unroll
    for (int j = 0; j < 4; ++j) {
        asv[j] = a_src[h * CDIM + j * 16 + r16];
        adv[j] = a_dst[h * CDIM + j * 16 + r16];
    }
#pragma unroll
    for (int i = 0; i < 2; ++i) {
        int rbase = row0 + w * 32 + i * 16 + (lane >> 4) * 4;
#pragma unroll
        for (int rr = 0; rr < 4; ++rr) {
            float ss = acc[i][0][rr] * asv[0] + acc[i][1][rr] * asv[1]
                     + acc[i][2][rr] * asv[2] + acc[i][3][rr] * asv[3];
            float dd = acc[i][0][rr] * adv[0] + acc[i][1][rr] * adv[1]
                     + acc[i][2][rr] * adv[2] + acc[i][3][rr] * adv[3];
#pragma unroll
            for (int off = 1; off < 16; off <<= 1) {
                ss += __shfl_xor(ss, off);
                dd += __shfl_xor(dd, off);
            }
            int row = rbase + rr;
            if ((lane & 15) == 0 && row < M) {
                al_s[row * HEADS + h] = ss;
                al_d[row * HEADS + h] = dd;
            }
        }
#pragma unroll
        for (int j = 0; j < 4; ++j) {
            int col = col0 + j * 16 + r16;
#pragma unroll
            for (int rr = 0; rr < 4; ++rr)
                if (rbase + rr < M) xtb[(size_t)(rbase + rr) * HID + col] = f2bf(acc[i][j][rr]);
        }
    }
}

// ---------------------------------------------------------------- CSR build
__global__ __launch_bounds__(256) void count_edges(const int* __restrict__ ei,
                                                   int* __restrict__ counts) {
    int e = blockIdx.x * 256 + threadIdx.x;
    if (e < E_TOT) {
        int dst = (e < E_EDGES) ? ei[E_EDGES + e] : (e - E_EDGES);
        atomicAdd(&counts[dst], 1);
    }
}

// scan_local + find_bounds folded (block 0 also binary-searches graph bounds)
__global__ __launch_bounds__(1024) void scan_local(const int* __restrict__ counts,
                                                   int* __restrict__ incl,
                                                   int* __restrict__ bsum,
                                                   const int* __restrict__ batch,
                                                   int* __restrict__ bounds) {
    __shared__ int s[1024];
    int tid = threadIdx.x;
    int i = blockIdx.x * 1024 + tid;
    if (blockIdx.x == 0 && tid <= B_GRAPHS) {
        int lo = 0, hi = N_NODES;
        while (lo < hi) {
            int mid = (lo + hi) >> 1;
            if (batch[mid] < tid) lo = mid + 1; else hi = mid;
        }
        bounds[tid] = lo;
    }
    int v = (i < N_NODES) ? counts[i] : 0;
    s[tid] = v;
    __syncthreads();
    for (int off = 1; off < 1024; off <<= 1) {
        int t = (tid >= off) ? s[tid - off] : 0;
        __syncthreads();
        s[tid] += t;
        __syncthreads();
    }
    if (i < N_NODES) incl[i] = s[tid];
    if (tid == 1023) bsum[blockIdx.x] = s[1023];
}

// scan_finalize with inline block-prefix (<=20 ints, summed by thread 0)
__global__ __launch_bounds__(1024) void scan_finalize(const int* __restrict__ counts,
                                                      const int* __restrict__ incl,
                                                      const int* __restrict__ bsum,
                                                      int* __restrict__ offsets,
                                                      int* __restrict__ cursor) {
    __shared__ int bpre_s;
    if (threadIdx.x == 0) {
        int s = 0;
        for (int j = 0; j < blockIdx.x; ++j) s += bsum[j];
        bpre_s = s;
    }
    __syncthreads();
    int i = blockIdx.x * 1024 + threadIdx.x;
    if (i < N_NODES) {
        int inc = incl[i] + bpre_s;
        offsets[i + 1] = inc;
        cursor[i] = inc - counts[i];
    }
    if (i == 0) offsets[0] = 0;
}

// stores srcn DIRECTLY (self-loop: srcn = dst) -> aggregation needs no ei load, no branch
__global__ __launch_bounds__(256) void scatter_edges(const int* __restrict__ ei,
                                                     int* __restrict__ cursor,
                                                     int* __restrict__ csr) {
    int e = blockIdx.x * 256 + threadIdx.x;
    if (e < E_TOT) {
        int srcn, dst;
        if (e < E_EDGES) { srcn = ei[e]; dst = ei[E_EDGES + e]; }
        else             { srcn = dst = e - E_EDGES; }
        int pos = atomicAdd(&cursor[dst], 1);
        csr[pos] = srcn;
    }
}

// ---------------------------------------------------------------- GAT aggregation: wave per node, lane owns 8 channels
// (round-10 version: VGPR 32, no spill, 4-way unrolled MLP — measured 55 us, ~3.6 TB/s = gather-pattern roofline)
__global__ __launch_bounds__(256) void gat_aggregate4(const unsigned short* __restrict__ xtb,
                                                      const float* __restrict__ al_s,
                                                      const float* __restrict__ al_d,
                                                      const int* __restrict__ offsets,
                                                      const int* __restrict__ csr,
                                                      const float* __restrict__ bias,
                                                      unsigned short* __restrict__ outHi,
                                                      unsigned short* __restrict__ outLo) {
    const int lane = threadIdx.x & 63;
    const int n = blockIdx.x * 4 + (threadIdx.x >> 6);
    const int h = lane >> 3;            // head of this lane's channels
    const int c0 = lane * 8;            // channels c0..c0+7
    const int beg = offsets[n];
    const int deg = offsets[n + 1] - beg;
    const float aldv = al_d[n * HEADS + h];

    float acc[8] = {};
    float psum = 0.f;

#pragma unroll 4
    for (int i = 0; i < deg; ++i) {
        int srcn = csr[beg + i];                            // broadcast, src resolved
        float ev = al_s[srcn * HEADS + h] + aldv;
        ev = (ev >= 0.f) ? ev : 0.2f * ev;
        float p = __expf(ev);       // native v_exp; no max-subtraction: ev is O(1), fp32-safe
        psum += p;
        short8 row = *(const short8*)(xtb + (size_t)srcn * HID + c0);
#pragma unroll
        for (int j = 0; j < 8; ++j)
            acc[j] = fmaf(p, bf2f((unsigned short)row[j]), acc[j]);
    }

    const float inv = 1.f / (psum + 1e-16f);
    float4 b0 = *(const float4*)(bias + c0);
    float4 b1 = *(const float4*)(bias + c0 + 4);
    float bv[8] = { b0.x, b0.y, b0.z, b0.w, b1.x, b1.y, b1.z, b1.w };
    short8 h8, l8;
#pragma unroll
    for (int j = 0; j < 8; ++j) {
        float v = acc[j] * inv + bv[j];
        v = (v > 0.f) ? v : expm1f(v);      // ELU
        unsigned short hi = f2bf(v);
        h8[j] = (short)hi;
        l8[j] = (short)f2bf(v - bf2f(hi));
    }
    size_t o = (size_t)n * HID + c0;
    *(short8*)(outHi + o) = h8;
    *(short8*)(outLo + o) = l8;
}

// ---------------------------------------------------------------- pooling stage A:
// grid (B_GRAPHS, 8 ch-blocks, 4 node-splits); 8 nodes in flight per block
__global__ __launch_bounds__(256) void pool_partial(const unsigned short* __restrict__ hHi,
                                                    const unsigned short* __restrict__ hLo,
                                                    const int* __restrict__ bounds,
                                                    float* __restrict__ partial) {
    const int b = blockIdx.x, y = blockIdx.y, k = blockIdx.z;
    const int s = bounds[b], cnt = bounds[b + 1] - s;
    const int ns = s + (cnt * k) / 4;
    const int ne = s + (cnt * (k + 1)) / 4;
    const int t = threadIdx.x;
    const int chp = t & 31;            // u32 pair within 64-ch block
    const int nl = t >> 5;             // 0..7

    float a0 = 0.f, a1 = 0.f;
    for (int n = ns + nl; n < ne; n += 8) {
        size_t off = (size_t)n * HID + y * 64 + chp * 2;
        unsigned vh = *(const unsigned*)(hHi + off);
        unsigned vl = *(const unsigned*)(hLo + off);
        a0 += bf2f((unsigned short)(vh & 0xffff)) + bf2f((unsigned short)(vl & 0xffff));
        a1 += bf2f((unsigned short)(vh >> 16)) + bf2f((unsigned short)(vl >> 16));
    }
    __shared__ float red[4][32][2];
    a0 += __shfl_xor(a0, 32);
    a1 += __shfl_xor(a1, 32);
    if ((t & 63) < 32) { red[t >> 6][chp][0] = a0; red[t >> 6][chp][1] = a1; }
    __syncthreads();
    if (t < 64) {
        int cp = t >> 1, c = t & 1;
        float v = red[0][cp][c] + red[1][cp][c] + red[2][cp][c] + red[3][cp][c];
        partial[(((size_t)k * B_GRAPHS + b) * 8 + y) * 64 + cp * 2 + c] = v;
    }
}

// ---------------------------------------------------------------- pool stage B + classifier + softmax (merged)
__global__ __launch_bounds__(512) void pool_classify(const float* __restrict__ partial,
                                                     const int* __restrict__ bounds,
                                                     const float* __restrict__ Wl,
                                                     const float* __restrict__ bl,
                                                     float* __restrict__ hG,
                                                     float* __restrict__ outP) {
    const int b = blockIdx.x, t = threadIdx.x;
    __shared__ float row[HID];
    __shared__ float logit[NCLS];
    float v = 0.f;
#pragma unroll
    for (int k = 0; k < 4; ++k)
        v += partial[((size_t)k * B_GRAPHS + b) * HID + t];
    float cnt = fmaxf((float)(bounds[b + 1] - bounds[b]), 1.0f);
    v /= cnt;
    hG[b * HID + t] = v;
    row[t] = v;
    __syncthreads();
    if (t < NCLS) {
        float acc = bl[t];
        for (int j = 0; j < HID; ++j) acc += row[j] * Wl[j * NCLS + t];
        logit[t] = acc;
    }
    __syncthreads();
    if (t == 0) {
        float mx = logit[0];
        for (int k = 1; k < NCLS; ++k) mx = fmaxf(mx, logit[k]);
        float ssum = 0.f, ex[NCLS];
        for (int k = 0; k < NCLS; ++k) { ex[k] = expf(logit[k] - mx); ssum += ex[k]; }
        for (int k = 0; k < NCLS; ++k) outP[b * NCLS + k] = ex[k] / ssum;
    }
}

// ---------------------------------------------------------------- launch
extern "C" void kernel_launch(void* const* d_in, const int* in_sizes, int n_in,
                              void* d_out, int out_size, void* d_ws, size_t ws_size,
                              hipStream_t stream) {
    const float* x     = (const float*)d_in[0];
    const int*   ei    = (const int*)d_in[1];
    const int*   batch = (const int*)d_in[2];
    const float* W[3]  = { (const float*)d_in[3], (const float*)d_in[7],  (const float*)d_in[11] };
    const float* as_[3] = { (const float*)d_in[4], (const float*)d_in[8],  (const float*)d_in[12] };
    const float* ad_[3] = { (const float*)d_in[5], (const float*)d_in[9],  (const float*)d_in[13] };
    const float* bb[3] = { (const float*)d_in[6], (const float*)d_in[10], (const float*)d_in[14] };
    const float* Wl    = (const float*)d_in[15];
    const float* bl    = (const float*)d_in[16];

    // workspace layout
    char* ws = (char*)d_ws;
    unsigned short* A1hi = (unsigned short*)ws;      ws += (size_t)M_PAD * F_INF * 2;  // 10.3 MB
    unsigned short* A1lo = (unsigned short*)ws;      ws += (size_t)M_PAD * F_INF * 2;
    unsigned short* A2hi = (unsigned short*)ws;      ws += (size_t)M_PAD * HID * 2;    // 20.6 MB
    unsigned short* A2lo = (unsigned short*)ws;      ws += (size_t)M_PAD * HID * 2;
    unsigned short* Bthi = (unsigned short*)ws;      ws += (size_t)HID * HID * 2;      // 0.5 MB
    unsigned short* Btlo = (unsigned short*)ws;      ws += (size_t)HID * HID * 2;
    unsigned short* xtb  = (unsigned short*)ws;      ws += (size_t)N_NODES * HID * 2;  // 20.5 MB
    float* als  = (float*)ws;                        ws += (size_t)N_NODES * HEADS * 4;
    float* ald  = (float*)ws;                        ws += (size_t)N_NODES * HEADS * 4;
    float* partial = (float*)ws;                     ws += (size_t)4 * B_GRAPHS * HID * 4; // 512 KB
    int* counts  = (int*)ws;                         ws += (size_t)N_NODES * 4;
    int* incl    = (int*)ws;                         ws += (size_t)N_NODES * 4;
    int* bsum    = (int*)ws;                         ws += 32 * 4;
    int* offsets = (int*)ws;                         ws += (size_t)(N_NODES + 1) * 4;
    int* cursor  = (int*)ws;                         ws += (size_t)N_NODES * 4;
    int* csr     = (int*)ws;                         ws += (size_t)E_TOT * 4;
    int* bounds  = (int*)ws;                         ws += (size_t)(B_GRAPHS + 1) * 4;

    float* hG = (float*)d_out;                 // 64*512
    float* probs = (float*)d_out + (size_t)B_GRAPHS * HID;

    // ---- CSR build (identical every call; rebuilt for determinism/no-caching)
    hipMemsetAsync(counts, 0, (size_t)N_NODES * 4, stream);
    count_edges<<<(E_TOT + 255) / 256, 256, 0, stream>>>(ei, counts);
    scan_local<<<NSCAN, 1024, 0, stream>>>(counts, incl, bsum, batch, bounds);
    scan_finalize<<<NSCAN, 1024, 0, stream>>>(counts, incl, bsum, offsets, cursor);
    scatter_edges<<<(E_TOT + 255) / 256, 256, 0, stream>>>(ei, cursor, csr);
    hipMemsetAsync(A2hi + (size_t)N_NODES * HID, 0, (size_t)(M_PAD - N_NODES) * HID * 2, stream);
    hipMemsetAsync(A2lo + (size_t)N_NODES * HID, 0, (size_t)(M_PAD - N_NODES) * HID * 2, stream);

    // ---- layer 1 (K = 256)
    {
        long totA = (long)M_PAD * F_INF;
        split_pad<<<(int)(totA / 4 / 256), 256, 0, stream>>>(x, A1hi, A1lo, N_NODES, F_INF, totA);
        transpose_split_B<<<dim3(HID / 32, F_INF / 32), 256, 0, stream>>>(W[0], Bthi, Btlo, F_INF);
        gemm_mfma<<<NWG_GEMM, 256, 0, stream>>>(A1hi, A1lo, Bthi, Btlo, as_[0], ad_[0],
                                                xtb, als, ald, N_NODES, F_INF);
        gat_aggregate4<<<N_NODES / 4, 256, 0, stream>>>(xtb, als, ald, offsets, csr, bb[0], A2hi, A2lo);
    }

    // ---- layers 2,3 (K = 512)
    for (int L = 1; L < 3; ++L) {
        transpose_split_B<<<dim3(HID / 32, HID / 32), 256, 0, stream>>>(W[L], Bthi, Btlo, HID);
        gemm_mfma<<<NWG_GEMM, 256, 0, stream>>>(A2hi, A2lo, Bthi, Btlo, as_[L], ad_[L],
                                                xtb, als, ald, N_NODES, HID);
        gat_aggregate4<<<N_NODES / 4, 256, 0, stream>>>(xtb, als, ald, offsets, csr, bb[L], A2hi, A2lo);
    }

    // ---- pool + classify
    {
        dim3 pgrid(B_GRAPHS, 8, 4);
        pool_partial<<<pgrid, 256, 0, stream>>>(A2hi, A2lo, bounds, partial);
        pool_classify<<<B_GRAPHS, 512, 0, stream>>>(partial, bounds, Wl, bl, hG, probs);
    }
}

// Round 13
// 367.492 us; speedup vs baseline: 1.1853x; 1.0323x over previous
//
#include <hip/hip_runtime.h>
#include <hip/hip_bf16.h>
#include <math.h>

#define N_NODES  20000
#define E_EDGES  320000
#define E_TOT    (E_EDGES + N_NODES)
#define F_INF    256
#define HEADS    8
#define CDIM     64
#define HID      512
#define B_GRAPHS 64
#define NCLS     10
#define M_PAD    20096          // 157 * 128
#define NSCAN    20             // ceil(20000/1024)
#define NWG_GEMM 1256           // 157 row-panels * 8 col-tiles (64 wide)

typedef __attribute__((ext_vector_type(8))) short short8;
typedef __attribute__((ext_vector_type(4))) float f32x4;

__device__ inline unsigned short f2bf(float x) {
    unsigned u = __builtin_bit_cast(unsigned, x);
    u += 0x7fff + ((u >> 16) & 1);          // round-to-nearest-even
    return (unsigned short)(u >> 16);
}
__device__ inline float bf2f(unsigned short h) {
    unsigned u = ((unsigned)h) << 16;
    return __builtin_bit_cast(float, u);
}

#define GLOAD_LDS16(g, l) __builtin_amdgcn_global_load_lds(                     \
        (const __attribute__((address_space(1))) void*)(g),                     \
        (__attribute__((address_space(3))) void*)(l), 16, 0, 0)

// ---------------------------------------------------------------- fp32 -> bf16 hi/lo split (row-padded)
__global__ __launch_bounds__(256) void split_pad(const float* __restrict__ src,
                                                 unsigned short* __restrict__ hi,
                                                 unsigned short* __restrict__ lo,
                                                 int M, int K, long total) {
    long i = ((long)blockIdx.x * 256 + threadIdx.x) * 4;
    if (i >= total) return;
    int row = (int)(i / K);
    float4 v = make_float4(0.f, 0.f, 0.f, 0.f);
    if (row < M) v = *(const float4*)(src + i);
    ushort4 h, l;
    h.x = f2bf(v.x); l.x = f2bf(v.x - bf2f(h.x));
    h.y = f2bf(v.y); l.y = f2bf(v.y - bf2f(h.y));
    h.z = f2bf(v.z); l.z = f2bf(v.z - bf2f(h.z));
    h.w = f2bf(v.w); l.w = f2bf(v.w - bf2f(h.w));
    *(ushort4*)(hi + i) = h;
    *(ushort4*)(lo + i) = l;
}

// ---------------------------------------------------------------- all 3 weight transposes in ONE launch
// grid (16, 16, 3); layer 0 (K=256) masks blockIdx.y >= 8
__global__ __launch_bounds__(256) void transpose_split_all(const float* __restrict__ W1,
                                                           const float* __restrict__ W2,
                                                           const float* __restrict__ W3,
                                                           unsigned short* __restrict__ B1h,
                                                           unsigned short* __restrict__ B1l,
                                                           unsigned short* __restrict__ B2h,
                                                           unsigned short* __restrict__ B2l,
                                                           unsigned short* __restrict__ B3h,
                                                           unsigned short* __restrict__ B3l) {
    const int L = blockIdx.z;
    const int K = (L == 0) ? F_INF : HID;
    if (blockIdx.y * 32 >= K) return;
    const float* B = (L == 0) ? W1 : (L == 1) ? W2 : W3;
    unsigned short* Bh = (L == 0) ? B1h : (L == 1) ? B2h : B3h;
    unsigned short* Bl = (L == 0) ? B1l : (L == 1) ? B2l : B3l;

    __shared__ float t[32][33];
    int n0 = blockIdx.x * 32, k0 = blockIdx.y * 32;
    int tx = threadIdx.x & 31, ty = threadIdx.x >> 5;     // 32 x 8
    for (int i = ty; i < 32; i += 8) t[i][tx] = B[(size_t)(k0 + i) * HID + n0 + tx];
    __syncthreads();
    for (int i = ty; i < 32; i += 8) {
        float v = t[tx][i];                                // = B[k0+tx][n0+i]
        unsigned short h = f2bf(v);
        unsigned short l = f2bf(v - bf2f(h));
        Bh[(size_t)(n0 + i) * K + k0 + tx] = h;
        Bl[(size_t)(n0 + i) * K + k0 + tx] = l;
    }
}

// ---------------------------------------------------------------- bf16x3 MFMA GEMM, 128x64 tile,
// double-buffered with COUNTED vmcnt (T4/m248v2): STAGE(next)=6 loads, then vmcnt(6) waits only for
// cur's 6 loads -> next tile's loads stay in flight across the raw barrier. Never drains to 0 mid-loop.
__global__ __launch_bounds__(256) void gemm_mfma(const unsigned short* __restrict__ Ahi,
                                                 const unsigned short* __restrict__ Alo,
                                                 const unsigned short* __restrict__ Bhi,
                                                 const unsigned short* __restrict__ Blo,
                                                 const float* __restrict__ a_src,
                                                 const float* __restrict__ a_dst,
                                                 unsigned short* __restrict__ xtb,
                                                 float* __restrict__ al_s,
                                                 float* __restrict__ al_d,
                                                 int M, int K) {
    __shared__ short AsHi[2][4096], AsLo[2][4096], BsHi[2][2048], BsLo[2][2048];   // 48 KB
    const int tid = threadIdx.x;
    const int w = tid >> 6, lane = tid & 63;

    // bijective XCD-chunked swizzle: nwg=1256, q=157, r=0 -> wg = xcd*157 + idx
    const int xcd = blockIdx.x & 7, idx = blockIdx.x >> 3;
    const int wg = xcd * (NWG_GEMM >> 3) + idx;
    const int row0 = (wg >> 3) * 128, col0 = (wg & 7) * 64;

    long offA[2];
    int ldsA[2];
#pragma unroll
    for (int i = 0; i < 2; ++i) {
        int u = w * 128 + i * 64 + lane;
        int row = u >> 2;
        int kg = (u & 3) ^ ((row >> 1) & 3);               // inverse of read swizzle
        offA[i] = ((long)(row0 + row) * K + kg * 8) * 2;   // bytes
        ldsA[i] = (w * 128 + i * 64) * 8;                  // short index
    }
    long offB;
    int ldsB;
    {
        int u = w * 64 + lane;
        int row = u >> 2;
        int kg = (u & 3) ^ ((row >> 1) & 3);
        offB = ((long)(col0 + row) * K + kg * 8) * 2;
        ldsB = (w * 64) * 8;
    }

    const int r16 = lane & 15, kg = lane >> 4;
    int aOff[2], bOff[4];
#pragma unroll
    for (int i = 0; i < 2; ++i) {
        int row = w * 32 + i * 16 + r16;
        aOff[i] = (row * 4 + (kg ^ ((row >> 1) & 3))) * 16;
    }
#pragma unroll
    for (int j = 0; j < 4; ++j) {
        int col = j * 16 + r16;
        bOff[j] = (col * 4 + (kg ^ ((col >> 1) & 3))) * 16;
    }

    const char* pAhi = (const char*)Ahi;
    const char* pAlo = (const char*)Alo;
    const char* pBhi = (const char*)Bhi;
    const char* pBlo = (const char*)Blo;

    f32x4 acc[2][4] = {};

#define STAGE(buf, kk) do {                                                      \
        long kb = (long)(kk) * 64;                                               \
        _Pragma("unroll")                                                        \
        for (int i_ = 0; i_ < 2; ++i_) {                                         \
            GLOAD_LDS16(pAhi + offA[i_] + kb, &AsHi[buf][ldsA[i_]]);             \
            GLOAD_LDS16(pAlo + offA[i_] + kb, &AsLo[buf][ldsA[i_]]);             \
        }                                                                        \
        GLOAD_LDS16(pBhi + offB + kb, &BsHi[buf][ldsB]);                         \
        GLOAD_LDS16(pBlo + offB + kb, &BsLo[buf][ldsB]);                         \
    } while (0)

#define COMPUTE(buf) do {                                                        \
        short8 fah[2], fal[2], fbh[4], fbl[4];                                   \
        _Pragma("unroll")                                                        \
        for (int i_ = 0; i_ < 2; ++i_) {                                         \
            fah[i_] = *(const short8*)((const char*)AsHi[buf] + aOff[i_]);       \
            fal[i_] = *(const short8*)((const char*)AsLo[buf] + aOff[i_]);       \
        }                                                                        \
        _Pragma("unroll")                                                        \
        for (int j_ = 0; j_ < 4; ++j_) {                                         \
            fbh[j_] = *(const short8*)((const char*)BsHi[buf] + bOff[j_]);       \
            fbl[j_] = *(const short8*)((const char*)BsLo[buf] + bOff[j_]);       \
        }                                                                        \
        _Pragma("unroll")                                                        \
        for (int i_ = 0; i_ < 2; ++i_)                                           \
            _Pragma("unroll")                                                    \
            for (int j_ = 0; j_ < 4; ++j_) {                                     \
                acc[i_][j_] = __builtin_amdgcn_mfma_f32_16x16x32_bf16(fah[i_], fbh[j_], acc[i_][j_], 0, 0, 0); \
                acc[i_][j_] = __builtin_amdgcn_mfma_f32_16x16x32_bf16(fah[i_], fbl[j_], acc[i_][j_], 0, 0, 0); \
                acc[i_][j_] = __builtin_amdgcn_mfma_f32_16x16x32_bf16(fal[i_], fbh[j_], acc[i_][j_], 0, 0, 0); \
            }                                                                    \
    } while (0)

    const int NS = K >> 5;
    STAGE(0, 0);
    int cur = 0;
    for (int t = 0; t < NS; ++t) {
        if (t + 1 < NS) {
            STAGE(cur ^ 1, t + 1);                         // 6 loads for next tile issued first
            asm volatile("s_waitcnt vmcnt(6)" ::: "memory"); // cur's 6 loads complete; next's in flight
        } else {
            asm volatile("s_waitcnt vmcnt(0)" ::: "memory"); // final tile: full drain
        }
        __builtin_amdgcn_s_barrier();                      // all waves' portions of cur landed
        COMPUTE(cur);
        __builtin_amdgcn_s_barrier();                      // all waves done reading cur before t+2 overwrites
        cur ^= 1;
    }

#undef STAGE
#undef COMPUTE

    // ---- epilogue. C/D layout: col=lane&15 within 16-block, row=(lane>>4)*4+rr.
    const int h = col0 >> 6;
    float asv[4], adv[4];
#pragma unroll
    for (int j = 0; j < 4; ++j) {
        asv[j] = a_src[h * CDIM + j * 16 + r16];
        adv[j] = a_dst[h * CDIM + j * 16 + r16];
    }
#pragma unroll
    for (int i = 0; i < 2; ++i) {
        int rbase = row0 + w * 32 + i * 16 + (lane >> 4) * 4;
#pragma unroll
        for (int rr = 0; rr < 4; ++rr) {
            float ss = acc[i][0][rr] * asv[0] + acc[i][1][rr] * asv[1]
                     + acc[i][2][rr] * asv[2] + acc[i][3][rr] * asv[3];
            float dd = acc[i][0][rr] * adv[0] + acc[i][1][rr] * adv[1]
                     + acc[i][2][rr] * adv[2] + acc[i][3][rr] * adv[3];
#pragma unroll
            for (int off = 1; off < 16; off <<= 1) {
                ss += __shfl_xor(ss, off);
                dd += __shfl_xor(dd, off);
            }
            int row = rbase + rr;
            if ((lane & 15) == 0 && row < M) {
                al_s[row * HEADS + h] = ss;
                al_d[row * HEADS + h] = dd;
            }
        }
#pragma unroll
        for (int j = 0; j < 4; ++j) {
            int col = col0 + j * 16 + r16;
#pragma unroll
            for (int rr = 0; rr < 4; ++rr)
                if (rbase + rr < M) xtb[(size_t)(rbase + rr) * HID + col] = f2bf(acc[i][j][rr]);
        }
    }
}

// ---------------------------------------------------------------- CSR build
__global__ __launch_bounds__(256) void count_edges(const int* __restrict__ ei,
                                                   int* __restrict__ counts) {
    int e = blockIdx.x * 256 + threadIdx.x;
    if (e < E_TOT) {
        int dst = (e < E_EDGES) ? ei[E_EDGES + e] : (e - E_EDGES);
        atomicAdd(&counts[dst], 1);
    }
}

// scan_local + find_bounds folded (block 0 also binary-searches graph bounds)
__global__ __launch_bounds__(1024) void scan_local(const int* __restrict__ counts,
                                                   int* __restrict__ incl,
                                                   int* __restrict__ bsum,
                                                   const int* __restrict__ batch,
                                                   int* __restrict__ bounds) {
    __shared__ int s[1024];
    int tid = threadIdx.x;
    int i = blockIdx.x * 1024 + tid;
    if (blockIdx.x == 0 && tid <= B_GRAPHS) {
        int lo = 0, hi = N_NODES;
        while (lo < hi) {
            int mid = (lo + hi) >> 1;
            if (batch[mid] < tid) lo = mid + 1; else hi = mid;
        }
        bounds[tid] = lo;
    }
    int v = (i < N_NODES) ? counts[i] : 0;
    s[tid] = v;
    __syncthreads();
    for (int off = 1; off < 1024; off <<= 1) {
        int t = (tid >= off) ? s[tid - off] : 0;
        __syncthreads();
        s[tid] += t;
        __syncthreads();
    }
    if (i < N_NODES) incl[i] = s[tid];
    if (tid == 1023) bsum[blockIdx.x] = s[1023];
}

// scan_finalize with inline block-prefix (<=20 ints, summed by thread 0)
__global__ __launch_bounds__(1024) void scan_finalize(const int* __restrict__ counts,
                                                      const int* __restrict__ incl,
                                                      const int* __restrict__ bsum,
                                                      int* __restrict__ offsets,
                                                      int* __restrict__ cursor) {
    __shared__ int bpre_s;
    if (threadIdx.x == 0) {
        int s = 0;
        for (int j = 0; j < blockIdx.x; ++j) s += bsum[j];
        bpre_s = s;
    }
    __syncthreads();
    int i = blockIdx.x * 1024 + threadIdx.x;
    if (i < N_NODES) {
        int inc = incl[i] + bpre_s;
        offsets[i + 1] = inc;
        cursor[i] = inc - counts[i];
    }
    if (i == 0) offsets[0] = 0;
}

// stores srcn DIRECTLY (self-loop: srcn = dst) -> aggregation needs no ei load, no branch
__global__ __launch_bounds__(256) void scatter_edges(const int* __restrict__ ei,
                                                     int* __restrict__ cursor,
                                                     int* __restrict__ csr) {
    int e = blockIdx.x * 256 + threadIdx.x;
    if (e < E_TOT) {
        int srcn, dst;
        if (e < E_EDGES) { srcn = ei[e]; dst = ei[E_EDGES + e]; }
        else             { srcn = dst = e - E_EDGES; }
        int pos = atomicAdd(&cursor[dst], 1);
        csr[pos] = srcn;
    }
}

// ---------------------------------------------------------------- GAT aggregation: wave per node, lane owns 8 channels
// (proven config: VGPR 32, no spill, 4-way unrolled MLP — 55 us, ~3.6 TB/s = gather-pattern roofline. UNCHANGED.)
__global__ __launch_bounds__(256) void gat_aggregate4(const unsigned short* __restrict__ xtb,
                                                      const float* __restrict__ al_s,
                                                      const float* __restrict__ al_d,
                                                      const int* __restrict__ offsets,
                                                      const int* __restrict__ csr,
                                                      const float* __restrict__ bias,
                                                      unsigned short* __restrict__ outHi,
                                                      unsigned short* __restrict__ outLo) {
    const int lane = threadIdx.x & 63;
    const int n = blockIdx.x * 4 + (threadIdx.x >> 6);
    const int h = lane >> 3;            // head of this lane's channels
    const int c0 = lane * 8;            // channels c0..c0+7
    const int beg = offsets[n];
    const int deg = offsets[n + 1] - beg;
    const float aldv = al_d[n * HEADS + h];

    float acc[8] = {};
    float psum = 0.f;

#pragma unroll 4
    for (int i = 0; i < deg; ++i) {
        int srcn = csr[beg + i];                            // broadcast, src resolved
        float ev = al_s[srcn * HEADS + h] + aldv;
        ev = (ev >= 0.f) ? ev : 0.2f * ev;
        float p = __expf(ev);       // native v_exp; no max-subtraction: ev is O(1), fp32-safe
        psum += p;
        short8 row = *(const short8*)(xtb + (size_t)srcn * HID + c0);
#pragma unroll
        for (int j = 0; j < 8; ++j)
            acc[j] = fmaf(p, bf2f((unsigned short)row[j]), acc[j]);
    }

    const float inv = 1.f / (psum + 1e-16f);
    float4 b0 = *(const float4*)(bias + c0);
    float4 b1 = *(const float4*)(bias + c0 + 4);
    float bv[8] = { b0.x, b0.y, b0.z, b0.w, b1.x, b1.y, b1.z, b1.w };
    short8 h8, l8;
#pragma unroll
    for (int j = 0; j < 8; ++j) {
        float v = acc[j] * inv + bv[j];
        v = (v > 0.f) ? v : expm1f(v);      // ELU
        unsigned short hi = f2bf(v);
        h8[j] = (short)hi;
        l8[j] = (short)f2bf(v - bf2f(hi));
    }
    size_t o = (size_t)n * HID + c0;
    *(short8*)(outHi + o) = h8;
    *(short8*)(outLo + o) = l8;
}

// ---------------------------------------------------------------- pooling stage A:
// grid (B_GRAPHS, 8 ch-blocks, 4 node-splits); 8 nodes in flight per block
__global__ __launch_bounds__(256) void pool_partial(const unsigned short* __restrict__ hHi,
                                                    const unsigned short* __restrict__ hLo,
                                                    const int* __restrict__ bounds,
                                                    float* __restrict__ partial) {
    const int b = blockIdx.x, y = blockIdx.y, k = blockIdx.z;
    const int s = bounds[b], cnt = bounds[b + 1] - s;
    const int ns = s + (cnt * k) / 4;
    const int ne = s + (cnt * (k + 1)) / 4;
    const int t = threadIdx.x;
    const int chp = t & 31;            // u32 pair within 64-ch block
    const int nl = t >> 5;             // 0..7

    float a0 = 0.f, a1 = 0.f;
    for (int n = ns + nl; n < ne; n += 8) {
        size_t off = (size_t)n * HID + y * 64 + chp * 2;
        unsigned vh = *(const unsigned*)(hHi + off);
        unsigned vl = *(const unsigned*)(hLo + off);
        a0 += bf2f((unsigned short)(vh & 0xffff)) + bf2f((unsigned short)(vl & 0xffff));
        a1 += bf2f((unsigned short)(vh >> 16)) + bf2f((unsigned short)(vl >> 16));
    }
    __shared__ float red[4][32][2];
    a0 += __shfl_xor(a0, 32);
    a1 += __shfl_xor(a1, 32);
    if ((t & 63) < 32) { red[t >> 6][chp][0] = a0; red[t >> 6][chp][1] = a1; }
    __syncthreads();
    if (t < 64) {
        int cp = t >> 1, c = t & 1;
        float v = red[0][cp][c] + red[1][cp][c] + red[2][cp][c] + red[3][cp][c];
        partial[(((size_t)k * B_GRAPHS + b) * 8 + y) * 64 + cp * 2 + c] = v;
    }
}

// ---------------------------------------------------------------- pool stage B + classifier + softmax (merged)
__global__ __launch_bounds__(512) void pool_classify(const float* __restrict__ partial,
                                                     const int* __restrict__ bounds,
                                                     const float* __restrict__ Wl,
                                                     const float* __restrict__ bl,
                                                     float* __restrict__ hG,
                                                     float* __restrict__ outP) {
    const int b = blockIdx.x, t = threadIdx.x;
    __shared__ float row[HID];
    __shared__ float logit[NCLS];
    float v = 0.f;
#pragma unroll
    for (int k = 0; k < 4; ++k)
        v += partial[((size_t)k * B_GRAPHS + b) * HID + t];
    float cnt = fmaxf((float)(bounds[b + 1] - bounds[b]), 1.0f);
    v /= cnt;
    hG[b * HID + t] = v;
    row[t] = v;
    __syncthreads();
    if (t < NCLS) {
        float acc = bl[t];
        for (int j = 0; j < HID; ++j) acc += row[j] * Wl[j * NCLS + t];
        logit[t] = acc;
    }
    __syncthreads();
    if (t == 0) {
        float mx = logit[0];
        for (int k = 1; k < NCLS; ++k) mx = fmaxf(mx, logit[k]);
        float ssum = 0.f, ex[NCLS];
        for (int k = 0; k < NCLS; ++k) { ex[k] = expf(logit[k] - mx); ssum += ex[k]; }
        for (int k = 0; k < NCLS; ++k) outP[b * NCLS + k] = ex[k] / ssum;
    }
}

// ---------------------------------------------------------------- launch
extern "C" void kernel_launch(void* const* d_in, const int* in_sizes, int n_in,
                              void* d_out, int out_size, void* d_ws, size_t ws_size,
                              hipStream_t stream) {
    const float* x     = (const float*)d_in[0];
    const int*   ei    = (const int*)d_in[1];
    const int*   batch = (const int*)d_in[2];
    const float* W[3]  = { (const float*)d_in[3], (const float*)d_in[7],  (const float*)d_in[11] };
    const float* as_[3] = { (const float*)d_in[4], (const float*)d_in[8],  (const float*)d_in[12] };
    const float* ad_[3] = { (const float*)d_in[5], (const float*)d_in[9],  (const float*)d_in[13] };
    const float* bb[3] = { (const float*)d_in[6], (const float*)d_in[10], (const float*)d_in[14] };
    const float* Wl    = (const float*)d_in[15];
    const float* bl    = (const float*)d_in[16];

    // workspace layout
    char* ws = (char*)d_ws;
    unsigned short* A1hi = (unsigned short*)ws;      ws += (size_t)M_PAD * F_INF * 2;  // 10.3 MB
    unsigned short* A1lo = (unsigned short*)ws;      ws += (size_t)M_PAD * F_INF * 2;
    unsigned short* A2hi = (unsigned short*)ws;      ws += (size_t)M_PAD * HID * 2;    // 20.6 MB
    unsigned short* A2lo = (unsigned short*)ws;      ws += (size_t)M_PAD * HID * 2;
    unsigned short* Bt1h = (unsigned short*)ws;      ws += (size_t)HID * F_INF * 2;    // weights, all 3 layers
    unsigned short* Bt1l = (unsigned short*)ws;      ws += (size_t)HID * F_INF * 2;
    unsigned short* Bt2h = (unsigned short*)ws;      ws += (size_t)HID * HID * 2;
    unsigned short* Bt2l = (unsigned short*)ws;      ws += (size_t)HID * HID * 2;
    unsigned short* Bt3h = (unsigned short*)ws;      ws += (size_t)HID * HID * 2;
    unsigned short* Bt3l = (unsigned short*)ws;      ws += (size_t)HID * HID * 2;
    unsigned short* xtb  = (unsigned short*)ws;      ws += (size_t)N_NODES * HID * 2;  // 20.5 MB
    float* als  = (float*)ws;                        ws += (size_t)N_NODES * HEADS * 4;
    float* ald  = (float*)ws;                        ws += (size_t)N_NODES * HEADS * 4;
    float* partial = (float*)ws;                     ws += (size_t)4 * B_GRAPHS * HID * 4; // 512 KB
    int* counts  = (int*)ws;                         ws += (size_t)N_NODES * 4;
    int* incl    = (int*)ws;                         ws += (size_t)N_NODES * 4;
    int* bsum    = (int*)ws;                         ws += 32 * 4;
    int* offsets = (int*)ws;                         ws += (size_t)(N_NODES + 1) * 4;
    int* cursor  = (int*)ws;                         ws += (size_t)N_NODES * 4;
    int* csr     = (int*)ws;                         ws += (size_t)E_TOT * 4;
    int* bounds  = (int*)ws;                         ws += (size_t)(B_GRAPHS + 1) * 4;

    float* hG = (float*)d_out;                 // 64*512
    float* probs = (float*)d_out + (size_t)B_GRAPHS * HID;

    // ---- upfront: all weight transposes (1 launch), A1 split, CSR build
    hipMemsetAsync(counts, 0, (size_t)N_NODES * 4, stream);
    transpose_split_all<<<dim3(16, 16, 3), 256, 0, stream>>>(W[0], W[1], W[2],
                                                             Bt1h, Bt1l, Bt2h, Bt2l, Bt3h, Bt3l);
    count_edges<<<(E_TOT + 255) / 256, 256, 0, stream>>>(ei, counts);
    scan_local<<<NSCAN, 1024, 0, stream>>>(counts, incl, bsum, batch, bounds);
    scan_finalize<<<NSCAN, 1024, 0, stream>>>(counts, incl, bsum, offsets, cursor);
    scatter_edges<<<(E_TOT + 255) / 256, 256, 0, stream>>>(ei, cursor, csr);
    hipMemsetAsync(A2hi + (size_t)N_NODES * HID, 0, (size_t)(M_PAD - N_NODES) * HID * 2, stream);
    hipMemsetAsync(A2lo + (size_t)N_NODES * HID, 0, (size_t)(M_PAD - N_NODES) * HID * 2, stream);
    {
        long totA = (long)M_PAD * F_INF;
        split_pad<<<(int)(totA / 4 / 256), 256, 0, stream>>>(x, A1hi, A1lo, N_NODES, F_INF, totA);
    }

    // ---- layer 1 (K = 256)
    gemm_mfma<<<NWG_GEMM, 256, 0, stream>>>(A1hi, A1lo, Bt1h, Bt1l, as_[0], ad_[0],
                                            xtb, als, ald, N_NODES, F_INF);
    gat_aggregate4<<<N_NODES / 4, 256, 0, stream>>>(xtb, als, ald, offsets, csr, bb[0], A2hi, A2lo);

    // ---- layer 2 (K = 512)
    gemm_mfma<<<NWG_GEMM, 256, 0, stream>>>(A2hi, A2lo, Bt2h, Bt2l, as_[1], ad_[1],
                                            xtb, als, ald, N_NODES, HID);
    gat_aggregate4<<<N_NODES / 4, 256, 0, stream>>>(xtb, als, ald, offsets, csr, bb[1], A2hi, A2lo);

    // ---- layer 3 (K = 512)
    gemm_mfma<<<NWG_GEMM, 256, 0, stream>>>(A2hi, A2lo, Bt3h, Bt3l, as_[2], ad_[2],
                                            xtb, als, ald, N_NODES, HID);
    gat_aggregate4<<<N_NODES / 4, 256, 0, stream>>>(xtb, als, ald, offsets, csr, bb[2], A2hi, A2lo);

    // ---- pool + classify
    {
        dim3 pgrid(B_GRAPHS, 8, 4);
        pool_partial<<<pgrid, 256, 0, stream>>>(A2hi, A2lo, bounds, partial);
        pool_classify<<<B_GRAPHS, 512, 0, stream>>>(partial, bounds, Wl, bl, hG, probs);
    }
}